// Round 1
// 254.249 us; speedup vs baseline: 1.0463x; 1.0463x over previous
//
#include <hip/hip_runtime.h>

#define NTOK 2048
#define HID 4096
#define NOUT 4096
#define NLORA 16
#define RANK 16

typedef float floatx4 __attribute__((ext_vector_type(4)));
typedef __bf16 bf16x8 __attribute__((ext_vector_type(8)));

__device__ __forceinline__ unsigned short f2b(float f) {
  unsigned int u = __float_as_uint(f);
  u += 0x7FFFu + ((u >> 16) & 1u);   // round-to-nearest-even
  return (unsigned short)(u >> 16);
}
__device__ __forceinline__ float b2f(unsigned short u) {
  return __uint_as_float(((unsigned int)u) << 16);
}
__device__ __forceinline__ unsigned int pk2(float a, float b) {
  return (unsigned int)f2b(a) | ((unsigned int)f2b(b) << 16);
}

// async global->LDS, 16 B/lane; LDS dest is wave-uniform base (+ lane*16 in HW)
__device__ __forceinline__ void gld16(const char* g, char* l) {
  __builtin_amdgcn_global_load_lds(
      (const __attribute__((address_space(1))) unsigned int*)g,
      (__attribute__((address_space(3))) unsigned int*)l,
      16, 0, 0);
}

// ---- inline per-wave dtype detection ----
__device__ __forceinline__ int detect_bf16(const void* xraw) {
  const int lane = threadIdx.x & 63;
  const int e = (((const unsigned short*)xraw)[2 * lane] >> 7) & 0xFF;
  const unsigned long long wild = __ballot(e < 96 || e > 159);
  return wild == 0ull;
}
__device__ __forceinline__ int detect_i64(const int* idxraw) {
  const int lane = threadIdx.x & 63;
  const unsigned long long nz = __ballot((lane & 1) && idxraw[lane] != 0);
  return nz == 0ull;
}

// ============ prep: axall slices (+X conversion side-effect) + W conversion ==
// blocks [0, 32*nks): axall: axpart[ks][t][n] = X(t, kslice) . Acat(n, kslice)
//   tile 128t x 128n, 4 waves of 64x64, BK=32, VGPR-staged fp32->bf16 (or bf16
//   direct). nt==0 blocks also write the converted X tile to xb.
// blocks [32*nks, +2048): W fp32->bf16 grid-stride conversion.
__global__ __launch_bounds__(256) void prep_kernel(
    const void* __restrict__ xv, const void* __restrict__ wv,
    const void* __restrict__ lav,
    unsigned short* __restrict__ xb, unsigned short* __restrict__ wb,
    float* __restrict__ axpart, int nks, int full) {
  const int tid = threadIdx.x;
  const int isb = detect_bf16(xv);
  const int AXB = 32 * nks;
  if (blockIdx.x >= AXB) {
    if (isb || !full) return;
    const int W8 = NOUT * HID / 8;
    const int cb = blockIdx.x - AXB;
    for (int i = cb * 256 + tid; i < W8; i += 2048 * 256) {
      const float4 a = ((const float4*)wv)[2 * i];
      const float4 b = ((const float4*)wv)[2 * i + 1];
      uint4 p;
      p.x = pk2(a.x, a.y); p.y = pk2(a.z, a.w);
      p.z = pk2(b.x, b.y); p.w = pk2(b.z, b.w);
      ((uint4*)wb)[i] = p;
    }
    return;
  }
  __shared__ char sm[16384];           // X 8KB @0, Acat 8KB @8192 (64B rows)
  const int b = blockIdx.x;
  const int tt = b & 15, nt = (b >> 4) & 1, ks = b >> 5;
  const int t0 = tt * 128, n0 = nt * 128;
  const int kslice = HID / nks;
  const int k0 = ks * kslice;
  const int wave = tid >> 6, lane = tid & 63;
  const int isx = tid < 128;
  const int row = isx ? tid : tid - 128;
  const size_t gbase = (size_t)((isx ? t0 : n0) + row) * HID + k0;
  const float* srcF = (isx ? (const float*)xv : (const float*)lav) + gbase;
  const unsigned short* srcB =
      (isx ? (const unsigned short*)xv : (const unsigned short*)lav) + gbase;
  char* ldsrow = sm + (isx ? 0 : 8192) + row * 64;
  const int prm = (tid >> 1) & 3;      // (row>>1)&3
  const int wrxb = (isx && nt == 0 && !isb && full);
  unsigned short* xbrow = xb + (size_t)(t0 + row) * HID + k0;

  const int wr = (wave >> 1) * 64, wc = (wave & 1) * 64;
  const int fm = lane & 15, fq = lane >> 4;
  const int sw2 = (fm >> 1) & 3;
  int aO[4], bO[4];
  #pragma unroll
  for (int i = 0; i < 4; ++i) {
    aO[i] = (wr + i * 16 + fm) * 64 + ((fq ^ sw2) << 4);
    bO[i] = 8192 + (wc + i * 16 + fm) * 64 + ((fq ^ sw2) << 4);
  }
  floatx4 acc[4][4];
  #pragma unroll
  for (int i = 0; i < 4; ++i)
    #pragma unroll
    for (int j = 0; j < 4; ++j) acc[i][j] = (floatx4){0.f, 0.f, 0.f, 0.f};

  const int NIT = kslice / 32;
  for (int it = 0; it < NIT; ++it) {
    uint4 w[4];
    if (isb) {
      const uint4* s4 = (const uint4*)(srcB + it * 32);
      #pragma unroll
      for (int g = 0; g < 4; ++g) w[g] = s4[g];
    } else {
      const float4* s4 = (const float4*)(srcF + it * 32);
      #pragma unroll
      for (int g = 0; g < 4; ++g) {
        const float4 f0 = s4[2 * g], f1 = s4[2 * g + 1];
        w[g].x = pk2(f0.x, f0.y); w[g].y = pk2(f0.z, f0.w);
        w[g].z = pk2(f1.x, f1.y); w[g].w = pk2(f1.z, f1.w);
      }
      if (wrxb) {
        uint4* d = (uint4*)(xbrow + it * 32);
        #pragma unroll
        for (int g = 0; g < 4; ++g) d[g] = w[g];
      }
    }
    #pragma unroll
    for (int g = 0; g < 4; ++g)
      *(uint4*)(ldsrow + ((g ^ prm) << 4)) = w[g];
    __syncthreads();
    bf16x8 af[4], bfv[4];
    #pragma unroll
    for (int i = 0; i < 4; ++i) af[i] = *(const bf16x8*)(sm + aO[i]);
    #pragma unroll
    for (int j = 0; j < 4; ++j) bfv[j] = *(const bf16x8*)(sm + bO[j]);
    #pragma unroll
    for (int i = 0; i < 4; ++i)
      #pragma unroll
      for (int j = 0; j < 4; ++j)
        acc[i][j] = __builtin_amdgcn_mfma_f32_16x16x32_bf16(af[i], bfv[j], acc[i][j], 0, 0, 0);
    __syncthreads();
  }
  const int c = lane & 15, rr = (lane >> 4) * 4;
  #pragma unroll
  for (int i = 0; i < 4; ++i)
    #pragma unroll
    for (int r = 0; r < 4; ++r) {
      const int t = t0 + wr + i * 16 + rr + r;
      float* dst = axpart + ((size_t)ks * NTOK + t) * 256 + n0 + wc;
      #pragma unroll
      for (int j = 0; j < 4; ++j) dst[j * 16 + c] = acc[i][j][r];
    }
}

// ============ main GEMM (+ fused bias & LoRA-B epilogue) =====================
// TM=256 x TN=128, 8 waves of 64x64 (4x4 frags, 16x16x32), BK=32, now with a
// 4-buffer / depth-3 counted-vmcnt pipeline (T3+T4): 9 gld16 in flight/wave,
// s_waitcnt vmcnt(6) + raw s_barrier per K-step — the gld16 queue is NEVER
// drained to 0 in the main loop, so HBM latency hides under MFMA.
// STAGE(k+3) is issued right after the barrier into buffer (k+3)&3, which was
// last read at stage k-1; every wave past the barrier has already issued its
// stage-(k-1) MFMAs, so those ds_read operands are consumed -> no WAR hazard.
// setprio(1) wraps the MFMA cluster (T5; pays once phases create role-split).
// Epilogue: ax/tok tables + bf16 lora_B (two 8-lora halves) cached in LDS.
__global__ __launch_bounds__(512, 2) void gemm_kernel(
    const void* __restrict__ x_raw, const void* __restrict__ w_raw,
    const unsigned short* __restrict__ xb_ws, const unsigned short* __restrict__ wb_ws,
    const void* __restrict__ bias_raw, const void* __restrict__ lorab_raw,
    const float* __restrict__ axpart, const int* __restrict__ idxraw,
    int nks, void* __restrict__ outv) {
  __shared__ char smem[98304];  // K-loop: buf b @ b*24576 (A 16K, B 8K), b=0..3
                                // phase2: Bl 32K @0, axs 16K @32768, tok @49152
  const int isb = detect_bf16(x_raw);
  const int i64 = detect_i64(idxraw);
  const unsigned short* Xb = isb ? (const unsigned short*)x_raw : xb_ws;
  const unsigned short* Wb = isb ? (const unsigned short*)w_raw : wb_ws;

  const int tid = threadIdx.x;
  const int wave = tid >> 6;
  const int lane = tid & 63;
  // XCD-compact: xcd owns 4 o-tiles x 8 t-tiles
  const int id = blockIdx.x;
  const int xcd = id & 7, slot = id >> 3;
  const int o0 = (xcd * 4 + (slot & 3)) * 128;
  const int t0 = (slot >> 2) * 256;
  const int wr = (wave >> 1) * 64;     // 4 row-groups of 64
  const int wc = (wave & 1) * 64;      // 2 col-groups of 64

  // staging: granule s covers row s>>2, stored q = s&3 = tile_q ^ ((row>>1)&3)
  const int q_ = ((lane & 3) ^ ((lane >> 3) & 3)) * 16;
  const int srw = (lane >> 2);
  const char* gA0 = (const char*)Xb + (size_t)(t0 + 0 + wave * 16 + srw) * (HID * 2) + q_;
  const char* gA1 = (const char*)Xb + (size_t)(t0 + 128 + wave * 16 + srw) * (HID * 2) + q_;
  const char* gB0 = (const char*)Wb + (size_t)(o0 + wave * 16 + srw) * (HID * 2) + q_;

  const int fm = lane & 15, fq = lane >> 4;
  const int sw2 = (fm >> 1) & 3;
  int aOff[4], bOff[4];
  #pragma unroll
  for (int i = 0; i < 4; ++i) {
    aOff[i] = (wr + i * 16 + fm) * 64 + ((fq ^ sw2) << 4);
    bOff[i] = 16384 + (wc + i * 16 + fm) * 64 + ((fq ^ sw2) << 4);
  }
  floatx4 acc[4][4];
  #pragma unroll
  for (int i = 0; i < 4; ++i)
    #pragma unroll
    for (int j = 0; j < 4; ++j) acc[i][j] = (floatx4){0.f, 0.f, 0.f, 0.f};

#define STAGE(K, B) do {                                  \
    const size_t kb_ = (size_t)(K) * 64;                  \
    char* d_ = smem + (B) * 24576 + wave * 1024;          \
    gld16(gA0 + kb_, d_);                                 \
    gld16(gA1 + kb_, d_ + 8192);                          \
    gld16(gB0 + kb_, d_ + 16384);                         \
  } while (0)

#define COMPUTE(B) do {                                                         \
    const char* base_ = smem + (B) * 24576;                                     \
    bf16x8 af[4], bfv[4];                                                       \
    _Pragma("unroll")                                                           \
    for (int i = 0; i < 4; ++i) af[i] = *(const bf16x8*)(base_ + aOff[i]);      \
    _Pragma("unroll")                                                           \
    for (int j = 0; j < 4; ++j) bfv[j] = *(const bf16x8*)(base_ + bOff[j]);     \
    __builtin_amdgcn_s_setprio(1);                                              \
    _Pragma("unroll")                                                           \
    for (int i = 0; i < 4; ++i)                                                 \
      _Pragma("unroll")                                                         \
      for (int j = 0; j < 4; ++j)                                               \
        acc[i][j] = __builtin_amdgcn_mfma_f32_16x16x32_bf16(af[i], bfv[j], acc[i][j], 0, 0, 0); \
    __builtin_amdgcn_s_setprio(0);                                              \
  } while (0)

  const int KITER = HID / 32;   // 128
  // ---- depth-3 pipelined K-loop, counted vmcnt, 1 barrier / K-step ----
  STAGE(0, 0);
  STAGE(1, 1);
  STAGE(2, 2);
  for (int k = 0; k < KITER - 3; ++k) {
    // 9 gld16/wave outstanding (stages k..k+2); vmcnt(6) => stage k landed.
    asm volatile("s_waitcnt vmcnt(6)" ::: "memory");
    __builtin_amdgcn_s_barrier();
    STAGE(k + 3, (k + 3) & 3);
    COMPUTE(k & 3);
  }
  // tail: stages KITER-3..KITER-1 still in flight; drain 6 -> 3 -> 0
  asm volatile("s_waitcnt vmcnt(6)" ::: "memory");
  __builtin_amdgcn_s_barrier();
  COMPUTE((KITER - 3) & 3);
  asm volatile("s_waitcnt vmcnt(3)" ::: "memory");
  __builtin_amdgcn_s_barrier();
  COMPUTE((KITER - 2) & 3);
  asm volatile("s_waitcnt vmcnt(0)" ::: "memory");
  __builtin_amdgcn_s_barrier();
  COMPUTE((KITER - 1) & 3);
#undef STAGE
#undef COMPUTE
  __syncthreads();

  // ---- phase 2a: build ax (slice-summed, l-window) + tok tables in LDS ----
  {
    const int t_l = tid >> 1, h8 = (tid & 1) * 8;
    const int t = t0 + t_l;
    int l = i64 ? idxraw[2 * t] : idxraw[t];
    if (l < 0 || l >= NLORA) l = -1;
    if ((tid & 1) == 0) *(int*)(smem + 49152 + t_l * 4) = l;
    float4 s0 = make_float4(0.f, 0.f, 0.f, 0.f), s1 = s0;
    if (l >= 0) {
      for (int s = 0; s < nks; ++s) {
        const float4* p = (const float4*)(axpart + ((size_t)s * NTOK + t) * 256 + l * 16 + h8);
        const float4 a = p[0], bq = p[1];
        s0.x += a.x; s0.y += a.y; s0.z += a.z; s0.w += a.w;
        s1.x += bq.x; s1.y += bq.y; s1.z += bq.z; s1.w += bq.w;
      }
    }
    float4* d = (float4*)(smem + 32768 + t_l * 64 + h8 * 4);
    d[0] = s0; d[1] = s1;
  }
  // bias (global, tiny)
  const int c = lane & 15;
  const int rr = (lane >> 4) * 4;
  float bv[4];
  #pragma unroll
  for (int j = 0; j < 4; ++j) {
    const int o = o0 + wc + j * 16 + c;
    bv[j] = isb ? b2f(((const unsigned short*)bias_raw)[o]) : ((const float*)bias_raw)[o];
  }
  // ---- phase 2b: two 8-lora halves of B cached in LDS as bf16 ----
  const int ol_ld = tid >> 2, rq = (tid & 3) * 4;
  #pragma unroll
  for (int h = 0; h < 2; ++h) {
    __syncthreads();
    #pragma unroll
    for (int lh = 0; lh < 8; ++lh) {
      const int l = h * 8 + lh;
      const size_t eoff = ((size_t)l * NOUT + o0 + ol_ld) * RANK + rq;
      uint2 pv;
      if (isb) {
        pv = *(const uint2*)((const unsigned short*)lorab_raw + eoff);
      } else {
        const float4 v = *(const float4*)((const float*)lorab_raw + eoff);
        pv.x = pk2(v.x, v.y); pv.y = pk2(v.z, v.w);
      }
      *(uint2*)(smem + lh * 4096 + ol_ld * 32 + rq * 2) = pv;
    }
    __syncthreads();
    #pragma unroll
    for (int mi = 0; mi < 4; ++mi) {
      #pragma unroll
      for (int r = 0; r < 4; ++r) {
        const int tl = wr + mi * 16 + rr + r;
        const int l = *(const int*)(smem + 49152 + tl * 4);
        if (l < 0 || (l >> 3) != h) continue;
        float axr[16];
        {
          const float4* ap = (const float4*)(smem + 32768 + tl * 64);
          #pragma unroll
          for (int g = 0; g < 4; ++g) {
            const float4 q = ap[g];
            axr[4 * g] = q.x; axr[4 * g + 1] = q.y;
            axr[4 * g + 2] = q.z; axr[4 * g + 3] = q.w;
          }
        }
        #pragma unroll
        for (int j = 0; j < 4; ++j) {
          const int ol = wc + j * 16 + c;
          const uint4 q0 = *(const uint4*)(smem + (l & 7) * 4096 + ol * 32);
          const uint4 q1 = *(const uint4*)(smem + (l & 7) * 4096 + ol * 32 + 16);
          float d = 0.f;
          const unsigned int qa[8] = {q0.x, q0.y, q0.z, q0.w, q1.x, q1.y, q1.z, q1.w};
          #pragma unroll
          for (int g = 0; g < 8; ++g) {
            d += b2f((unsigned short)(qa[g] & 0xFFFF)) * axr[2 * g];
            d += b2f((unsigned short)(qa[g] >> 16)) * axr[2 * g + 1];
          }
          acc[mi][j][r] += d;
        }
      }
    }
  }
  // ---- store ----
  unsigned short* outb = (unsigned short*)outv;
  float* outf = (float*)outv;
  #pragma unroll
  for (int mi = 0; mi < 4; ++mi) {
    #pragma unroll
    for (int r = 0; r < 4; ++r) {
      const size_t t = t0 + wr + mi * 16 + rr + r;
      #pragma unroll
      for (int j = 0; j < 4; ++j) {
        const int o = o0 + wc + j * 16 + c;
        const float v = acc[mi][j][r] + bv[j];
        const size_t oi = t * NOUT + o;
        if (isb) outb[oi] = f2b(v); else outf[oi] = v;
      }
    }
  }
}

extern "C" void kernel_launch(void* const* d_in, const int* in_sizes, int n_in,
                              void* d_out, int out_size, void* d_ws, size_t ws_size,
                              hipStream_t stream) {
  const void* x  = d_in[0];
  const void* w  = d_in[1];
  const void* bs = d_in[2];
  const void* la = d_in[3];
  const void* lb = d_in[4];
  const int*  ix = (const int*)d_in[5];

  const size_t xb_bytes = (size_t)NTOK * HID * 2;
  const size_t wb_bytes = (size_t)NOUT * HID * 2;
  const size_t ax1      = (size_t)NTOK * 256 * 4;   // one k-slice

  char* ws = (char*)d_ws;
  int nks, full;
  unsigned short *xb, *wb2;
  float* axp;
  if (ws_size >= xb_bytes + wb_bytes + 8 * ax1 + 64) {
    nks = 8; full = 1;
    xb = (unsigned short*)ws;
    wb2 = (unsigned short*)(ws + xb_bytes);
    axp = (float*)(ws + xb_bytes + wb_bytes);
  } else if (ws_size >= xb_bytes + wb_bytes + 2 * ax1 + 64) {
    nks = 2; full = 1;
    xb = (unsigned short*)ws;
    wb2 = (unsigned short*)(ws + xb_bytes);
    axp = (float*)(ws + xb_bytes + wb_bytes);
  } else {
    nks = 2; full = 0;                 // assume raw already bf16
    xb = (unsigned short*)x;
    wb2 = (unsigned short*)w;
    axp = (float*)ws;
  }

  prep_kernel<<<32 * nks + 2048, 256, 0, stream>>>(
      x, w, la, xb, wb2, axp, nks, full);
  gemm_kernel<<<256, 512, 0, stream>>>(
      x, w, xb, wb2, bs, lb, axp, ix, nks, d_out);
}